// Round 3
// baseline (134.017 us; speedup 1.0000x reference)
//
#include <hip/hip_runtime.h>
#include <math.h>

// Problem constants
constexpr int kB  = 8;
constexpr int kNL = 48;
constexpr int kNT = 512;
constexpr int kH  = 128;
constexpr int kG  = 10;

constexpr int kRowsL = kB * kNL;          // 384
constexpr int kRowsT = kB * kNT;          // 4096
constexpr int kRows  = kRowsL + kRowsT;   // 4480
constexpr int kM     = kB * kNL * kNT;    // 196608
constexpr float kEps = 1e-5f;

// Output layout (flat concat, reference return order)
constexpr size_t OFF_PI = 0;
constexpr size_t OFF_SG = (size_t)kM * kG;
constexpr size_t OFF_MU = 2 * (size_t)kM * kG;
constexpr size_t OFF_D  = 3 * (size_t)kM * kG;
constexpr size_t OFF_CB = OFF_D + kM;

typedef __attribute__((ext_vector_type(8))) short short8;   // 8 bf16 (4 VGPR)
typedef __attribute__((ext_vector_type(4))) float f32x4;    // MFMA C/D

__device__ __forceinline__ short f2bf(float f) {            // RNE float->bf16
    unsigned u = __builtin_bit_cast(unsigned, f);
    unsigned r = u + 0x7fffu + ((u >> 16) & 1u);
    return (short)(r >> 16);
}
__device__ __forceinline__ float elu_f(float x) {
    return x > 0.0f ? x : (__expf(x) - 1.0f);
}

// ---------------------------------------------------------------------------
// prep_fused: [4480x128] @ (BN-scaled W1)^T via bf16 MFMA, self-packing.
// Each block (one 16-row mtile) builds its own B-fragments from global W1
// (coalesced-ish float4 reads, L2-resident after first blocks), folding the
// BN scale s[c]=gamma*rsqrt(var+eps); ligand rows also get the folded bias.
// Rows 0..383 -> Al, rest -> At. Grid: 280 blocks x 256 (4 waves x 2 ntiles).
// ---------------------------------------------------------------------------
__global__ __launch_bounds__(256) void prep_fused(
    const float* __restrict__ lig_s, const float* __restrict__ pro_s,
    const float* __restrict__ W1, const float* __restrict__ b1,
    const float* __restrict__ gamma, const float* __restrict__ beta,
    const float* __restrict__ mean, const float* __restrict__ var,
    float* __restrict__ Al, float* __restrict__ At)
{
    const int mtile = blockIdx.x;                 // 0..279
    const int wave = threadIdx.x >> 6, lane = threadIdx.x & 63;
    const int q = lane >> 4, n16 = lane & 15;
    const bool lig = (mtile < kRowsL / 16);       // uniform per block

    // Build B-fragments: B[k][c] = W1[c][k] * s[c]
    // frag layout: c = ntile*16 + (lane&15), k = kt*32 + (lane>>4)*8 + j
    short8 bfrag[2][4];
    float bi[2];
#pragma unroll
    for (int h = 0; h < 2; ++h) {
        const int c = (2 * wave + h) * 16 + n16;
        const float sc = gamma[c] * rsqrtf(var[c] + kEps);
        bi[h] = lig ? ((b1[c] - mean[c]) * sc + beta[c]) : 0.0f;
        const float* wr = W1 + (size_t)c * kH;
#pragma unroll
        for (int kt = 0; kt < 4; ++kt) {
            const float4* w4 = (const float4*)(wr + kt * 32 + q * 8);
            float4 w0 = w4[0], w1 = w4[1];
            short8 v;
            v[0] = f2bf(w0.x * sc); v[1] = f2bf(w0.y * sc);
            v[2] = f2bf(w0.z * sc); v[3] = f2bf(w0.w * sc);
            v[4] = f2bf(w1.x * sc); v[5] = f2bf(w1.y * sc);
            v[6] = f2bf(w1.z * sc); v[7] = f2bf(w1.w * sc);
            bfrag[h][kt] = v;
        }
    }

    const int row = mtile * 16 + n16;
    const float* X = lig ? (lig_s + (size_t)row * kH)
                         : (pro_s + (size_t)(row - kRowsL) * kH);

    f32x4 acc[2] = {};
#pragma unroll
    for (int kt = 0; kt < 4; ++kt) {
        const float4* xp = (const float4*)(X + kt * 32 + q * 8);
        float4 x0 = xp[0], x1 = xp[1];
        short8 a;
        a[0] = f2bf(x0.x); a[1] = f2bf(x0.y); a[2] = f2bf(x0.z); a[3] = f2bf(x0.w);
        a[4] = f2bf(x1.x); a[5] = f2bf(x1.y); a[6] = f2bf(x1.z); a[7] = f2bf(x1.w);
        acc[0] = __builtin_amdgcn_mfma_f32_16x16x32_bf16(a, bfrag[0][kt], acc[0], 0, 0, 0);
        acc[1] = __builtin_amdgcn_mfma_f32_16x16x32_bf16(a, bfrag[1][kt], acc[1], 0, 0, 0);
    }

#pragma unroll
    for (int h = 0; h < 2; ++h) {
        const int c = (2 * wave + h) * 16 + n16;
#pragma unroll
        for (int r = 0; r < 4; ++r) {
            const int R = mtile * 16 + q * 4 + r;
            const float v = acc[h][r] + bi[h];
            if (lig) Al[(size_t)R * kH + c] = v;
            else     At[(size_t)(R - kRowsL) * kH + c] = v;
        }
    }
}

// ---------------------------------------------------------------------------
// pair_fused: per wave, 32 consecutive pairs (2 mtiles) sharing one ligand
// row. C-frag = bf16(elu(Al[bl]+At[pr])); the 3 projection weights built as
// resident B-frags from global. Epilogue: softmax across 16-lane n-group,
// elu+c; outputs staged in LDS (wave's 32 pairs are m-contiguous) and stored
// with 5 fully-coalesced dword stores per region. dist + batch id fused.
// Grid: 384*4 blocks x 256 thr; block = (bl, 128-t chunk); wave = 32 t's.
// ---------------------------------------------------------------------------
__global__ __launch_bounds__(256) void pair_fused(
    const float* __restrict__ Al, const float* __restrict__ At,
    const float* __restrict__ Wpi, const float* __restrict__ bpi,
    const float* __restrict__ Wsg, const float* __restrict__ bsg,
    const float* __restrict__ Wmu, const float* __restrict__ bmu,
    const float* __restrict__ lig_pos, const float* __restrict__ pro_pos,
    float* __restrict__ out)
{
    const int blk = blockIdx.x;
    const int bl = blk >> 2, tch = blk & 3;
    const int wave = threadIdx.x >> 6, lane = threadIdx.x & 63;
    const int q = lane >> 4, n = lane & 15;
    const int b = bl / kNL;
    const int t0 = tch * 128 + wave * 32;

    // Projection B-frags: B[k][n] = W[n][k]; rows n>=10 are zero.
    short8 bf[3][4];
#pragma unroll
    for (int ntl = 0; ntl < 3; ++ntl) {
        const float* W = (ntl == 0) ? Wpi : ((ntl == 1) ? Wsg : Wmu);
#pragma unroll
        for (int kt = 0; kt < 4; ++kt) {
            short8 v;
            if (n < kG) {
                const float4* w4 = (const float4*)(W + (size_t)n * kH + kt * 32 + q * 8);
                float4 w0 = w4[0], w1 = w4[1];
                v[0] = f2bf(w0.x); v[1] = f2bf(w0.y); v[2] = f2bf(w0.z); v[3] = f2bf(w0.w);
                v[4] = f2bf(w1.x); v[5] = f2bf(w1.y); v[6] = f2bf(w1.z); v[7] = f2bf(w1.w);
            } else {
#pragma unroll
                for (int j = 0; j < 8; ++j) v[j] = 0;
            }
            bf[ntl][kt] = v;
        }
    }
    const float bias0 = (n < kG) ? bpi[n] : 0.0f;
    const float bias1 = (n < kG) ? bsg[n] : 0.0f;
    const float bias2 = (n < kG) ? bmu[n] : 0.0f;

    // Hoist the (block-uniform) ligand row.
    const float* alp = Al + (size_t)bl * kH;
    float4 al[4][2];
#pragma unroll
    for (int kt = 0; kt < 4; ++kt) {
        const float4* ap4 = (const float4*)(alp + kt * 32 + q * 8);
        al[kt][0] = ap4[0]; al[kt][1] = ap4[1];
    }

    f32x4 acc[2][3] = {};
#pragma unroll
    for (int mt = 0; mt < 2; ++mt) {
        const int t = t0 + mt * 16 + n;
        const float* atp = At + (size_t)(b * kNT + t) * kH;
#pragma unroll
        for (int kt = 0; kt < 4; ++kt) {
            const float4* tp4 = (const float4*)(atp + kt * 32 + q * 8);
            float4 t0v = tp4[0], t1v = tp4[1];
            const float4 a0 = al[kt][0], a1 = al[kt][1];
            short8 a;
            a[0] = f2bf(elu_f(a0.x + t0v.x)); a[1] = f2bf(elu_f(a0.y + t0v.y));
            a[2] = f2bf(elu_f(a0.z + t0v.z)); a[3] = f2bf(elu_f(a0.w + t0v.w));
            a[4] = f2bf(elu_f(a1.x + t1v.x)); a[5] = f2bf(elu_f(a1.y + t1v.y));
            a[6] = f2bf(elu_f(a1.z + t1v.z)); a[7] = f2bf(elu_f(a1.w + t1v.w));
            acc[mt][0] = __builtin_amdgcn_mfma_f32_16x16x32_bf16(a, bf[0][kt], acc[mt][0], 0, 0, 0);
            acc[mt][1] = __builtin_amdgcn_mfma_f32_16x16x32_bf16(a, bf[1][kt], acc[mt][1], 0, 0, 0);
            acc[mt][2] = __builtin_amdgcn_mfma_f32_16x16x32_bf16(a, bf[2][kt], acc[mt][2], 0, 0, 0);
        }
    }

    // Stage epilogue results in LDS: per wave 3 x 320 floats (m-contiguous).
    __shared__ float st[4][3 * 320];
    float* sw = st[wave];

#pragma unroll
    for (int mt = 0; mt < 2; ++mt) {
#pragma unroll
        for (int r = 0; r < 4; ++r) {
            const int sl = (mt * 16 + q * 4 + r) * kG;   // pair-local slot
            // pi: masked softmax across the 16-lane n-group
            const float lg = acc[mt][0][r] + bias0;
            float mx = (n < kG) ? lg : -3.0e38f;
#pragma unroll
            for (int d = 1; d < 16; d <<= 1) mx = fmaxf(mx, __shfl_xor(mx, d));
            const float e = (n < kG) ? __expf(lg - mx) : 0.0f;
            float sm = e;
#pragma unroll
            for (int d = 1; d < 16; d <<= 1) sm += __shfl_xor(sm, d);
            if (n < kG) {
                sw[sl + n]           = e / sm;
                sw[320 + sl + n]     = elu_f(acc[mt][1][r] + bias1) + 1.1f;
                sw[640 + sl + n]     = elu_f(acc[mt][2][r] + bias2) + 1.0f;
            }
        }
    }
    __syncthreads();

    // Coalesced stores: wave's 32 pairs occupy contiguous [pairbase*10, +320).
    const int pairbase = bl * kNT + t0;
    float* pib = out + OFF_PI + (size_t)pairbase * kG;
    float* sgb = out + OFF_SG + (size_t)pairbase * kG;
    float* mub = out + OFF_MU + (size_t)pairbase * kG;
#pragma unroll
    for (int i = 0; i < 5; ++i) {
        pib[i * 64 + lane] = sw[i * 64 + lane];
        sgb[i * 64 + lane] = sw[320 + i * 64 + lane];
        mub[i * 64 + lane] = sw[640 + i * 64 + lane];
    }

    // dist + batch id (lanes 0..31 cover the wave's 32 t's)
    if (lane < 32) {
        const int t = t0 + lane;
        const int pr = b * kNT + t;
        const int m = bl * kNT + t;
        const float dx = lig_pos[(size_t)bl * 3 + 0] - pro_pos[(size_t)pr * 3 + 0];
        const float dy = lig_pos[(size_t)bl * 3 + 1] - pro_pos[(size_t)pr * 3 + 1];
        const float dz = lig_pos[(size_t)bl * 3 + 2] - pro_pos[(size_t)pr * 3 + 2];
        out[OFF_D + m] = sqrtf(dx * dx + dy * dy + dz * dz);
        out[OFF_CB + m] = (float)b;
    }
}

extern "C" void kernel_launch(void* const* d_in, const int* in_sizes, int n_in,
                              void* d_out, int out_size, void* d_ws, size_t ws_size,
                              hipStream_t stream) {
    (void)in_sizes; (void)n_in; (void)out_size; (void)ws_size;
    const float* lig_s    = (const float*)d_in[0];
    const float* lig_pos  = (const float*)d_in[1];
    const float* pro_s    = (const float*)d_in[3];
    const float* pro_pos  = (const float*)d_in[4];
    const float* W1       = (const float*)d_in[6];
    const float* b1       = (const float*)d_in[7];
    const float* bn_gamma = (const float*)d_in[8];
    const float* bn_beta  = (const float*)d_in[9];
    const float* bn_mean  = (const float*)d_in[10];
    const float* bn_var   = (const float*)d_in[11];
    const float* W_pi     = (const float*)d_in[12];
    const float* b_pi     = (const float*)d_in[13];
    const float* W_sigma  = (const float*)d_in[14];
    const float* b_sigma  = (const float*)d_in[15];
    const float* W_mu     = (const float*)d_in[16];
    const float* b_mu     = (const float*)d_in[17];

    float* out = (float*)d_out;
    float* Al  = (float*)d_ws;                               // 384*128 f32
    float* At  = Al + (size_t)kRowsL * kH;                   // 4096*128 f32

    prep_fused<<<kRows / 16, 256, 0, stream>>>(
        lig_s, pro_s, W1, b1, bn_gamma, bn_beta, bn_mean, bn_var, Al, At);
    pair_fused<<<kRowsL * 4, 256, 0, stream>>>(
        Al, At, W_pi, b_pi, W_sigma, b_sigma, W_mu, b_mu,
        lig_pos, pro_pos, out);
}

// Round 4
// 133.943 us; speedup vs baseline: 1.0005x; 1.0005x over previous
//
#include <hip/hip_runtime.h>
#include <math.h>

// Problem constants
constexpr int kB  = 8;
constexpr int kNL = 48;
constexpr int kNT = 512;
constexpr int kH  = 128;
constexpr int kG  = 10;

constexpr int kRowsL = kB * kNL;          // 384
constexpr int kRowsT = kB * kNT;          // 4096
constexpr int kRows  = kRowsL + kRowsT;   // 4480
constexpr int kM     = kB * kNL * kNT;    // 196608
constexpr float kEps = 1e-5f;

// Output layout (flat concat, reference return order)
constexpr size_t OFF_PI = 0;
constexpr size_t OFF_SG = (size_t)kM * kG;
constexpr size_t OFF_MU = 2 * (size_t)kM * kG;
constexpr size_t OFF_D  = 3 * (size_t)kM * kG;
constexpr size_t OFF_CB = OFF_D + kM;

typedef __attribute__((ext_vector_type(8))) short short8;   // 8 bf16 (4 VGPR)
typedef __attribute__((ext_vector_type(4))) float f32x4;    // MFMA C/D

__device__ __forceinline__ short f2bf(float f) {            // RNE float->bf16
    unsigned u = __builtin_bit_cast(unsigned, f);
    unsigned r = u + 0x7fffu + ((u >> 16) & 1u);
    return (short)(r >> 16);
}
__device__ __forceinline__ float elu_f(float x) {
    return x > 0.0f ? x : (__expf(x) - 1.0f);
}

// ---------------------------------------------------------------------------
// prep_fused: [4480x128] @ (BN-scaled W1)^T via bf16 MFMA, self-packing.
// Each block (one 16-row mtile) builds its own B-fragments from global W1,
// folding BN scale s[c]=gamma*rsqrt(var+eps); ligand rows get folded bias.
// Rows 0..383 -> Al, rest -> At. Grid: 280 blocks x 256 (4 waves x 2 ntiles).
// ---------------------------------------------------------------------------
__global__ __launch_bounds__(256) void prep_fused(
    const float* __restrict__ lig_s, const float* __restrict__ pro_s,
    const float* __restrict__ W1, const float* __restrict__ b1,
    const float* __restrict__ gamma, const float* __restrict__ beta,
    const float* __restrict__ mean, const float* __restrict__ var,
    float* __restrict__ Al, float* __restrict__ At)
{
    const int mtile = blockIdx.x;                 // 0..279
    const int wave = threadIdx.x >> 6, lane = threadIdx.x & 63;
    const int q = lane >> 4, n16 = lane & 15;
    const bool lig = (mtile < kRowsL / 16);       // uniform per block (384=24*16)

    // B-fragments: B[k][c] = W1[c][k] * s[c]
    // layout: c = ntile*16 + (lane&15), k = kt*32 + (lane>>4)*8 + j
    short8 bfrag[2][4];
    float bi[2];
#pragma unroll
    for (int h = 0; h < 2; ++h) {
        const int c = (2 * wave + h) * 16 + n16;
        const float sc = gamma[c] * rsqrtf(var[c] + kEps);
        bi[h] = lig ? ((b1[c] - mean[c]) * sc + beta[c]) : 0.0f;
        const float* wr = W1 + (size_t)c * kH;
#pragma unroll
        for (int kt = 0; kt < 4; ++kt) {
            const float4* w4 = (const float4*)(wr + kt * 32 + q * 8);
            float4 w0 = w4[0], w1 = w4[1];
            short8 v;
            v[0] = f2bf(w0.x * sc); v[1] = f2bf(w0.y * sc);
            v[2] = f2bf(w0.z * sc); v[3] = f2bf(w0.w * sc);
            v[4] = f2bf(w1.x * sc); v[5] = f2bf(w1.y * sc);
            v[6] = f2bf(w1.z * sc); v[7] = f2bf(w1.w * sc);
            bfrag[h][kt] = v;
        }
    }

    const int row = mtile * 16 + n16;
    const float* X = lig ? (lig_s + (size_t)row * kH)
                         : (pro_s + (size_t)(row - kRowsL) * kH);

    f32x4 acc[2] = {};
#pragma unroll
    for (int kt = 0; kt < 4; ++kt) {
        const float4* xp = (const float4*)(X + kt * 32 + q * 8);
        float4 x0 = xp[0], x1 = xp[1];
        short8 a;
        a[0] = f2bf(x0.x); a[1] = f2bf(x0.y); a[2] = f2bf(x0.z); a[3] = f2bf(x0.w);
        a[4] = f2bf(x1.x); a[5] = f2bf(x1.y); a[6] = f2bf(x1.z); a[7] = f2bf(x1.w);
        acc[0] = __builtin_amdgcn_mfma_f32_16x16x32_bf16(a, bfrag[0][kt], acc[0], 0, 0, 0);
        acc[1] = __builtin_amdgcn_mfma_f32_16x16x32_bf16(a, bfrag[1][kt], acc[1], 0, 0, 0);
    }

#pragma unroll
    for (int h = 0; h < 2; ++h) {
        const int c = (2 * wave + h) * 16 + n16;
#pragma unroll
        for (int r = 0; r < 4; ++r) {
            const int R = mtile * 16 + q * 4 + r;
            const float v = acc[h][r] + bi[h];
            if (lig) Al[(size_t)R * kH + c] = v;
            else     At[(size_t)(R - kRowsL) * kH + c] = v;
        }
    }
}

// ---------------------------------------------------------------------------
// pair_fused: per wave, 32 consecutive pairs (2 mtiles) sharing one ligand
// row. A-frag = bf16(elu(Al[bl]+At[pr])); 3 projection weights resident as
// B-frags built from global (L2-hit). Epilogue: softmax across the 16-lane
// n-group via shfl_xor, elu+c, direct predicated stores (best-measured
// epilogue, round 2). dist + batch id fused on lanes 0..31.
// Grid: 384*4 blocks x 256 thr; block = (bl, 128-t chunk); wave = 32 t's.
// ---------------------------------------------------------------------------
__global__ __launch_bounds__(256) void pair_fused(
    const float* __restrict__ Al, const float* __restrict__ At,
    const float* __restrict__ Wpi, const float* __restrict__ bpi,
    const float* __restrict__ Wsg, const float* __restrict__ bsg,
    const float* __restrict__ Wmu, const float* __restrict__ bmu,
    const float* __restrict__ lig_pos, const float* __restrict__ pro_pos,
    float* __restrict__ out)
{
    const int blk = blockIdx.x;
    const int bl = blk >> 2, tch = blk & 3;
    const int wave = threadIdx.x >> 6, lane = threadIdx.x & 63;
    const int q = lane >> 4, n = lane & 15;
    const int b = bl / kNL;
    const int t0 = tch * 128 + wave * 32;

    // Projection B-frags: B[k][n] = W[n][k]; rows n>=10 zero.
    short8 bf[3][4];
#pragma unroll
    for (int ntl = 0; ntl < 3; ++ntl) {
        const float* W = (ntl == 0) ? Wpi : ((ntl == 1) ? Wsg : Wmu);
#pragma unroll
        for (int kt = 0; kt < 4; ++kt) {
            short8 v;
            if (n < kG) {
                const float4* w4 = (const float4*)(W + (size_t)n * kH + kt * 32 + q * 8);
                float4 w0 = w4[0], w1 = w4[1];
                v[0] = f2bf(w0.x); v[1] = f2bf(w0.y); v[2] = f2bf(w0.z); v[3] = f2bf(w0.w);
                v[4] = f2bf(w1.x); v[5] = f2bf(w1.y); v[6] = f2bf(w1.z); v[7] = f2bf(w1.w);
            } else {
#pragma unroll
                for (int j = 0; j < 8; ++j) v[j] = 0;
            }
            bf[ntl][kt] = v;
        }
    }
    const float bias0 = (n < kG) ? bpi[n] : 0.0f;
    const float bias1 = (n < kG) ? bsg[n] : 0.0f;
    const float bias2 = (n < kG) ? bmu[n] : 0.0f;

    // Hoist the (block-uniform) ligand row.
    const float* alp = Al + (size_t)bl * kH;
    float4 al[4][2];
#pragma unroll
    for (int kt = 0; kt < 4; ++kt) {
        const float4* ap4 = (const float4*)(alp + kt * 32 + q * 8);
        al[kt][0] = ap4[0]; al[kt][1] = ap4[1];
    }

    f32x4 acc[2][3] = {};
#pragma unroll
    for (int mt = 0; mt < 2; ++mt) {
        const int t = t0 + mt * 16 + n;
        const float* atp = At + (size_t)(b * kNT + t) * kH;
#pragma unroll
        for (int kt = 0; kt < 4; ++kt) {
            const float4* tp4 = (const float4*)(atp + kt * 32 + q * 8);
            float4 t0v = tp4[0], t1v = tp4[1];
            const float4 a0 = al[kt][0], a1 = al[kt][1];
            short8 a;
            a[0] = f2bf(elu_f(a0.x + t0v.x)); a[1] = f2bf(elu_f(a0.y + t0v.y));
            a[2] = f2bf(elu_f(a0.z + t0v.z)); a[3] = f2bf(elu_f(a0.w + t0v.w));
            a[4] = f2bf(elu_f(a1.x + t1v.x)); a[5] = f2bf(elu_f(a1.y + t1v.y));
            a[6] = f2bf(elu_f(a1.z + t1v.z)); a[7] = f2bf(elu_f(a1.w + t1v.w));
            acc[mt][0] = __builtin_amdgcn_mfma_f32_16x16x32_bf16(a, bf[0][kt], acc[mt][0], 0, 0, 0);
            acc[mt][1] = __builtin_amdgcn_mfma_f32_16x16x32_bf16(a, bf[1][kt], acc[mt][1], 0, 0, 0);
            acc[mt][2] = __builtin_amdgcn_mfma_f32_16x16x32_bf16(a, bf[2][kt], acc[mt][2], 0, 0, 0);
        }
    }

    const int pairbase = bl * kNT + t0;
#pragma unroll
    for (int mt = 0; mt < 2; ++mt) {
#pragma unroll
        for (int r = 0; r < 4; ++r) {
            const int m = pairbase + mt * 16 + q * 4 + r;
            // pi: masked softmax across the 16-lane n-group
            const float lg = acc[mt][0][r] + bias0;
            float mx = (n < kG) ? lg : -3.0e38f;
#pragma unroll
            for (int d = 1; d < 16; d <<= 1) mx = fmaxf(mx, __shfl_xor(mx, d));
            const float e = (n < kG) ? __expf(lg - mx) : 0.0f;
            float sm = e;
#pragma unroll
            for (int d = 1; d < 16; d <<= 1) sm += __shfl_xor(sm, d);
            if (n < kG) {
                out[OFF_PI + (size_t)m * kG + n] = e / sm;
                out[OFF_SG + (size_t)m * kG + n] = elu_f(acc[mt][1][r] + bias1) + 1.1f;
                out[OFF_MU + (size_t)m * kG + n] = elu_f(acc[mt][2][r] + bias2) + 1.0f;
            }
        }
    }

    // dist + batch id (lanes 0..31 cover the wave's 32 t's)
    if (lane < 32) {
        const int t = t0 + lane;
        const int pr = b * kNT + t;
        const int m = bl * kNT + t;
        const float dx = lig_pos[(size_t)bl * 3 + 0] - pro_pos[(size_t)pr * 3 + 0];
        const float dy = lig_pos[(size_t)bl * 3 + 1] - pro_pos[(size_t)pr * 3 + 1];
        const float dz = lig_pos[(size_t)bl * 3 + 2] - pro_pos[(size_t)pr * 3 + 2];
        out[OFF_D + m] = sqrtf(dx * dx + dy * dy + dz * dz);
        out[OFF_CB + m] = (float)b;
    }
}

extern "C" void kernel_launch(void* const* d_in, const int* in_sizes, int n_in,
                              void* d_out, int out_size, void* d_ws, size_t ws_size,
                              hipStream_t stream) {
    (void)in_sizes; (void)n_in; (void)out_size; (void)ws_size;
    const float* lig_s    = (const float*)d_in[0];
    const float* lig_pos  = (const float*)d_in[1];
    const float* pro_s    = (const float*)d_in[3];
    const float* pro_pos  = (const float*)d_in[4];
    const float* W1       = (const float*)d_in[6];
    const float* b1       = (const float*)d_in[7];
    const float* bn_gamma = (const float*)d_in[8];
    const float* bn_beta  = (const float*)d_in[9];
    const float* bn_mean  = (const float*)d_in[10];
    const float* bn_var   = (const float*)d_in[11];
    const float* W_pi     = (const float*)d_in[12];
    const float* b_pi     = (const float*)d_in[13];
    const float* W_sigma  = (const float*)d_in[14];
    const float* b_sigma  = (const float*)d_in[15];
    const float* W_mu     = (const float*)d_in[16];
    const float* b_mu     = (const float*)d_in[17];

    float* out = (float*)d_out;
    float* Al  = (float*)d_ws;                               // 384*128 f32
    float* At  = Al + (size_t)kRowsL * kH;                   // 4096*128 f32

    prep_fused<<<kRows / 16, 256, 0, stream>>>(
        lig_s, pro_s, W1, b1, bn_gamma, bn_beta, bn_mean, bn_var, Al, At);
    pair_fused<<<kRowsL * 4, 256, 0, stream>>>(
        Al, At, W_pi, b_pi, W_sigma, b_sigma, W_mu, b_mu,
        lig_pos, pro_pos, out);
}

// Round 5
// 127.931 us; speedup vs baseline: 1.0476x; 1.0470x over previous
//
#include <hip/hip_runtime.h>
#include <math.h>

// Problem constants
constexpr int kB  = 8;
constexpr int kNL = 48;
constexpr int kNT = 512;
constexpr int kH  = 128;
constexpr int kG  = 10;

constexpr int kRowsL = kB * kNL;          // 384
constexpr int kRowsT = kB * kNT;          // 4096
constexpr int kRows  = kRowsL + kRowsT;   // 4480
constexpr int kM     = kB * kNL * kNT;    // 196608
constexpr float kEps = 1e-5f;

// Output layout (flat concat, reference return order)
constexpr size_t OFF_PI = 0;
constexpr size_t OFF_SG = (size_t)kM * kG;
constexpr size_t OFF_MU = 2 * (size_t)kM * kG;
constexpr size_t OFF_D  = 3 * (size_t)kM * kG;
constexpr size_t OFF_CB = OFF_D + kM;

typedef __attribute__((ext_vector_type(8))) short short8;   // 8 bf16 (4 VGPR)
typedef __attribute__((ext_vector_type(4))) float f32x4;    // MFMA C/D

__device__ __forceinline__ short f2bf(float f) {            // RNE float->bf16
    unsigned u = __builtin_bit_cast(unsigned, f);
    unsigned r = u + 0x7fffu + ((u >> 16) & 1u);
    return (short)(r >> 16);
}
__device__ __forceinline__ float elu_f(float x) {
    return x > 0.0f ? x : (__expf(x) - 1.0f);
}

// ---------------------------------------------------------------------------
// pack: fold BN scale into W1, emit B-fragment-layout bf16 weight images.
//   W1p[kt][nt8][lane][j] = W1[c][k]*s[c],  c=nt*16+(lane&15), k=kt*32+(lane>>4)*8+j
//   Wcp[kt][nt3][lane][j] = Wcat[n][k]      (pi|sigma|mu rows, padded to 16 w/ 0)
//   bias_l[c] = (b1[c]-mean[c])*s[c]+beta[c]
// Pre-packing keeps the hot kernels' weight loads as coalesced dwordx4
// (round 2 measured 5 us faster than per-block self-packing, rounds 3/4).
// ---------------------------------------------------------------------------
__global__ __launch_bounds__(256) void pack_kernel(
    const float* __restrict__ W1, const float* __restrict__ b1,
    const float* __restrict__ gamma, const float* __restrict__ beta,
    const float* __restrict__ mean, const float* __restrict__ var,
    const float* __restrict__ Wpi, const float* __restrict__ Wsg,
    const float* __restrict__ Wmu,
    short* __restrict__ W1p, short* __restrict__ Wcp, float* __restrict__ bias_l)
{
    const int tid = threadIdx.x;
    __shared__ float s_s[kH];
    if (tid < kH) {
        float s = gamma[tid] * rsqrtf(var[tid] + kEps);
        s_s[tid] = s;
        bias_l[tid] = (b1[tid] - mean[tid]) * s + beta[tid];
    }
    __syncthreads();

    // W1p: 4 ktiles x 8 ntiles x 64 lanes, 8 bf16 each
    for (int idx = tid; idx < 4 * 8 * 64; idx += 256) {
        const int kt = idx >> 9, nt = (idx >> 6) & 7, lane = idx & 63;
        const int c  = nt * 16 + (lane & 15);
        const int k0 = kt * 32 + (lane >> 4) * 8;
        const float s = s_s[c];
        const float* wr = W1 + (size_t)c * kH + k0;
        short8 v;
#pragma unroll
        for (int j = 0; j < 8; ++j) v[j] = f2bf(wr[j] * s);
        *((short8*)W1p + idx) = v;
    }
    // Wcp: 4 ktiles x 3 ntiles x 64 lanes
    for (int idx = tid; idx < 4 * 3 * 64; idx += 256) {
        const int kt = idx / 192, rem = idx % 192, nt = rem >> 6, lane = rem & 63;
        const int n  = lane & 15;
        const int k0 = kt * 32 + (lane >> 4) * 8;
        const float* W = (nt == 0) ? Wpi : ((nt == 1) ? Wsg : Wmu);
        short8 v;
        if (n < kG) {
            const float* wr = W + (size_t)n * kH + k0;
#pragma unroll
            for (int j = 0; j < 8; ++j) v[j] = f2bf(wr[j]);
        } else {
#pragma unroll
            for (int j = 0; j < 8; ++j) v[j] = 0;
        }
        *((short8*)Wcp + idx) = v;
    }
}

// ---------------------------------------------------------------------------
// prep: [4480x128] @ W1s^T via bf16 MFMA. Rows 0..383 -> Al (+bias), rest -> At.
// Grid: 280 blocks (one 16-row mtile each), 4 waves, wave handles 2 ntiles.
// ---------------------------------------------------------------------------
__global__ __launch_bounds__(256) void prep_mfma(
    const float* __restrict__ lig_s, const float* __restrict__ pro_s,
    const short* __restrict__ W1p, const float* __restrict__ bias_l,
    float* __restrict__ Al, float* __restrict__ At)
{
    const int mtile = blockIdx.x;                 // 0..279
    const int wave = threadIdx.x >> 6, lane = threadIdx.x & 63;
    const int q = lane >> 4, n16 = lane & 15;

    short8 bfrag[2][4];
    const short8* wp = (const short8*)W1p;
#pragma unroll
    for (int kt = 0; kt < 4; ++kt)
#pragma unroll
        for (int h = 0; h < 2; ++h)
            bfrag[h][kt] = wp[(kt * 8 + (2 * wave + h)) * 64 + lane];

    const int row = mtile * 16 + n16;
    const bool lig = (row < kRowsL);              // uniform per block (384=24*16)
    const float* X = lig ? (lig_s + (size_t)row * kH)
                         : (pro_s + (size_t)(row - kRowsL) * kH);

    f32x4 acc[2] = {};
#pragma unroll
    for (int kt = 0; kt < 4; ++kt) {
        const float4* xp = (const float4*)(X + kt * 32 + q * 8);
        float4 x0 = xp[0], x1 = xp[1];
        short8 a;
        a[0] = f2bf(x0.x); a[1] = f2bf(x0.y); a[2] = f2bf(x0.z); a[3] = f2bf(x0.w);
        a[4] = f2bf(x1.x); a[5] = f2bf(x1.y); a[6] = f2bf(x1.z); a[7] = f2bf(x1.w);
        acc[0] = __builtin_amdgcn_mfma_f32_16x16x32_bf16(a, bfrag[0][kt], acc[0], 0, 0, 0);
        acc[1] = __builtin_amdgcn_mfma_f32_16x16x32_bf16(a, bfrag[1][kt], acc[1], 0, 0, 0);
    }

#pragma unroll
    for (int h = 0; h < 2; ++h) {
        const int c = (2 * wave + h) * 16 + n16;
        const float bi = lig ? bias_l[c] : 0.0f;
#pragma unroll
        for (int r = 0; r < 4; ++r) {
            const int R = mtile * 16 + q * 4 + r;
            const float v = acc[h][r] + bi;
            if (lig) Al[(size_t)R * kH + c] = v;
            else     At[(size_t)(R - kRowsL) * kH + c] = v;
        }
    }
}

// ---------------------------------------------------------------------------
// pair: per wave, 32 consecutive pairs (2 mtiles) sharing one ligand row.
//   A-frag = bf16(elu(Al[bl]+At[pr])), weights resident as B-frags (48 VGPR)
//   loaded coalesced from the pre-packed Wcp image.
//   Epilogue: softmax over the 16-lane n-group, elu+c, predicated stores;
//   dist + batch id fused on lanes 0..31.
// Grid: 384*4 blocks x 256 thr; block = (bl, 128-t chunk); wave = 32 t's.
// ---------------------------------------------------------------------------
__global__ __launch_bounds__(256) void pair_mfma(
    const float* __restrict__ Al, const float* __restrict__ At,
    const short* __restrict__ Wcp,
    const float* __restrict__ bpi, const float* __restrict__ bsg,
    const float* __restrict__ bmu,
    const float* __restrict__ lig_pos, const float* __restrict__ pro_pos,
    float* __restrict__ out)
{
    const int blk = blockIdx.x;
    const int bl = blk >> 2, tch = blk & 3;
    const int wave = threadIdx.x >> 6, lane = threadIdx.x & 63;
    const int q = lane >> 4, n = lane & 15;
    const int b = bl / kNL;
    const int t0 = tch * 128 + wave * 32;

    short8 bf[3][4];
    const short8* wp = (const short8*)Wcp;
#pragma unroll
    for (int kt = 0; kt < 4; ++kt)
#pragma unroll
        for (int ntl = 0; ntl < 3; ++ntl)
            bf[ntl][kt] = wp[(kt * 3 + ntl) * 64 + lane];

    const int nc = (n < kG) ? n : (kG - 1);
    const float bias0 = (n < kG) ? bpi[nc] : 0.0f;
    const float bias1 = (n < kG) ? bsg[nc] : 0.0f;
    const float bias2 = (n < kG) ? bmu[nc] : 0.0f;

    const float* alp = Al + (size_t)bl * kH;
    f32x4 acc[2][3] = {};

#pragma unroll
    for (int mt = 0; mt < 2; ++mt) {
        const int t = t0 + mt * 16 + n;
        const float* atp = At + (size_t)(b * kNT + t) * kH;
#pragma unroll
        for (int kt = 0; kt < 4; ++kt) {
            const float4* ap4 = (const float4*)(alp + kt * 32 + q * 8);
            const float4* tp4 = (const float4*)(atp + kt * 32 + q * 8);
            float4 a0 = ap4[0], a1 = ap4[1];
            float4 t0v = tp4[0], t1v = tp4[1];
            short8 a;
            a[0] = f2bf(elu_f(a0.x + t0v.x)); a[1] = f2bf(elu_f(a0.y + t0v.y));
            a[2] = f2bf(elu_f(a0.z + t0v.z)); a[3] = f2bf(elu_f(a0.w + t0v.w));
            a[4] = f2bf(elu_f(a1.x + t1v.x)); a[5] = f2bf(elu_f(a1.y + t1v.y));
            a[6] = f2bf(elu_f(a1.z + t1v.z)); a[7] = f2bf(elu_f(a1.w + t1v.w));
            acc[mt][0] = __builtin_amdgcn_mfma_f32_16x16x32_bf16(a, bf[0][kt], acc[mt][0], 0, 0, 0);
            acc[mt][1] = __builtin_amdgcn_mfma_f32_16x16x32_bf16(a, bf[1][kt], acc[mt][1], 0, 0, 0);
            acc[mt][2] = __builtin_amdgcn_mfma_f32_16x16x32_bf16(a, bf[2][kt], acc[mt][2], 0, 0, 0);
        }
    }

    const int pairbase = bl * kNT + t0;
#pragma unroll
    for (int mt = 0; mt < 2; ++mt) {
#pragma unroll
        for (int r = 0; r < 4; ++r) {
            const int m = pairbase + mt * 16 + q * 4 + r;
            // pi: masked softmax across the 16-lane n-group
            const float lg = acc[mt][0][r] + bias0;
            float mx = (n < kG) ? lg : -3.0e38f;
#pragma unroll
            for (int d = 1; d < 16; d <<= 1) mx = fmaxf(mx, __shfl_xor(mx, d));
            const float e = (n < kG) ? __expf(lg - mx) : 0.0f;
            float sm = e;
#pragma unroll
            for (int d = 1; d < 16; d <<= 1) sm += __shfl_xor(sm, d);
            if (n < kG) {
                out[OFF_PI + (size_t)m * kG + n] = e / sm;
                out[OFF_SG + (size_t)m * kG + n] = elu_f(acc[mt][1][r] + bias1) + 1.1f;
                out[OFF_MU + (size_t)m * kG + n] = elu_f(acc[mt][2][r] + bias2) + 1.0f;
            }
        }
    }

    // dist + batch id (lanes 0..31 cover the wave's 32 t's)
    if (lane < 32) {
        const int t = t0 + lane;
        const int pr = b * kNT + t;
        const int m = bl * kNT + t;
        const float dx = lig_pos[(size_t)bl * 3 + 0] - pro_pos[(size_t)pr * 3 + 0];
        const float dy = lig_pos[(size_t)bl * 3 + 1] - pro_pos[(size_t)pr * 3 + 1];
        const float dz = lig_pos[(size_t)bl * 3 + 2] - pro_pos[(size_t)pr * 3 + 2];
        out[OFF_D + m] = sqrtf(dx * dx + dy * dy + dz * dz);
        out[OFF_CB + m] = (float)b;
    }
}

extern "C" void kernel_launch(void* const* d_in, const int* in_sizes, int n_in,
                              void* d_out, int out_size, void* d_ws, size_t ws_size,
                              hipStream_t stream) {
    (void)in_sizes; (void)n_in; (void)out_size; (void)ws_size;
    const float* lig_s    = (const float*)d_in[0];
    const float* lig_pos  = (const float*)d_in[1];
    const float* pro_s    = (const float*)d_in[3];
    const float* pro_pos  = (const float*)d_in[4];
    const float* W1       = (const float*)d_in[6];
    const float* b1       = (const float*)d_in[7];
    const float* bn_gamma = (const float*)d_in[8];
    const float* bn_beta  = (const float*)d_in[9];
    const float* bn_mean  = (const float*)d_in[10];
    const float* bn_var   = (const float*)d_in[11];
    const float* W_pi     = (const float*)d_in[12];
    const float* b_pi     = (const float*)d_in[13];
    const float* W_sigma  = (const float*)d_in[14];
    const float* b_sigma  = (const float*)d_in[15];
    const float* W_mu     = (const float*)d_in[16];
    const float* b_mu     = (const float*)d_in[17];

    float* out = (float*)d_out;
    float* Al  = (float*)d_ws;                               // 384*128 f32
    float* At  = Al + (size_t)kRowsL * kH;                   // 4096*128 f32
    short* W1p = (short*)(At + (size_t)kRowsT * kH);         // 4*8*64*8 bf16
    short* Wcp = W1p + 4 * 8 * 64 * 8;                       // 4*3*64*8 bf16
    float* bias_l = (float*)(Wcp + 4 * 3 * 64 * 8);          // 128 f32

    pack_kernel<<<1, 256, 0, stream>>>(W1, b1, bn_gamma, bn_beta, bn_mean, bn_var,
                                       W_pi, W_sigma, W_mu, W1p, Wcp, bias_l);
    prep_mfma<<<kRows / 16, 256, 0, stream>>>(lig_s, pro_s, W1p, bias_l, Al, At);
    pair_mfma<<<kRowsL * 4, 256, 0, stream>>>(Al, At, Wcp, b_pi, b_sigma, b_mu,
                                              lig_pos, pro_pos, out);
}

// Round 6
// 124.992 us; speedup vs baseline: 1.0722x; 1.0235x over previous
//
#include <hip/hip_runtime.h>
#include <math.h>

// Problem constants
constexpr int kB  = 8;
constexpr int kNL = 48;
constexpr int kNT = 512;
constexpr int kH  = 128;
constexpr int kG  = 10;

constexpr int kRowsL = kB * kNL;          // 384
constexpr int kRowsT = kB * kNT;          // 4096
constexpr int kRows  = kRowsL + kRowsT;   // 4480
constexpr int kM     = kB * kNL * kNT;    // 196608
constexpr float kEps = 1e-5f;

// Output layout (flat concat, reference return order)
constexpr size_t OFF_PI = 0;
constexpr size_t OFF_SG = (size_t)kM * kG;
constexpr size_t OFF_MU = 2 * (size_t)kM * kG;
constexpr size_t OFF_D  = 3 * (size_t)kM * kG;
constexpr size_t OFF_CB = OFF_D + kM;

typedef __attribute__((ext_vector_type(8))) short short8;   // 8 bf16 (4 VGPR)
typedef __attribute__((ext_vector_type(4))) float f32x4;    // MFMA C/D

__device__ __forceinline__ short f2bf(float f) {            // RNE float->bf16
    unsigned u = __builtin_bit_cast(unsigned, f);
    unsigned r = u + 0x7fffu + ((u >> 16) & 1u);
    return (short)(r >> 16);
}
__device__ __forceinline__ float elu_f(float x) {
    return x > 0.0f ? x : (__expf(x) - 1.0f);
}

// ---------------------------------------------------------------------------
// prep_sp: [4480x128] @ (BN-scaled W1)^T via bf16 MFMA, self-packing W1
// fragments per block (cheap at 280 blocks; verified rounds 3/4). Block 280
// additionally packs the Wcp projection-weight fragment image so the 1536-
// block pair kernel keeps its coalesced pre-packed loads (round-5 winner)
// without a separate serialized single-block pack launch.
// ---------------------------------------------------------------------------
__global__ __launch_bounds__(256) void prep_sp(
    const float* __restrict__ lig_s, const float* __restrict__ pro_s,
    const float* __restrict__ W1, const float* __restrict__ b1,
    const float* __restrict__ gamma, const float* __restrict__ beta,
    const float* __restrict__ mean, const float* __restrict__ var,
    const float* __restrict__ Wpi, const float* __restrict__ Wsg,
    const float* __restrict__ Wmu,
    float* __restrict__ Al, float* __restrict__ At, short* __restrict__ Wcp)
{
    const int mtile = blockIdx.x;                 // 0..280
    const int tid = threadIdx.x;

    if (mtile == kRows / 16) {
        // ---- Wcp packer: 4 ktiles x 3 ntiles x 64 lanes, 8 bf16 each ----
        for (int idx = tid; idx < 4 * 3 * 64; idx += 256) {
            const int kt = idx / 192, rem = idx % 192, nt = rem >> 6, lane = rem & 63;
            const int n  = lane & 15;
            const int k0 = kt * 32 + (lane >> 4) * 8;
            const float* W = (nt == 0) ? Wpi : ((nt == 1) ? Wsg : Wmu);
            short8 v;
            if (n < kG) {
                const float* wr = W + (size_t)n * kH + k0;
#pragma unroll
                for (int j = 0; j < 8; ++j) v[j] = f2bf(wr[j]);
            } else {
#pragma unroll
                for (int j = 0; j < 8; ++j) v[j] = 0;
            }
            *((short8*)Wcp + idx) = v;
        }
        return;
    }

    const int wave = tid >> 6, lane = tid & 63;
    const int q = lane >> 4, n16 = lane & 15;
    const bool lig = (mtile < kRowsL / 16);       // uniform per block (384=24*16)

    // Self-pack B-fragments: B[k][c] = W1[c][k] * s[c]
    // layout: c = ntile*16 + (lane&15), k = kt*32 + (lane>>4)*8 + j
    short8 bfrag[2][4];
    float bi[2];
#pragma unroll
    for (int h = 0; h < 2; ++h) {
        const int c = (2 * wave + h) * 16 + n16;
        const float sc = gamma[c] * rsqrtf(var[c] + kEps);
        bi[h] = lig ? ((b1[c] - mean[c]) * sc + beta[c]) : 0.0f;
        const float* wr = W1 + (size_t)c * kH;
#pragma unroll
        for (int kt = 0; kt < 4; ++kt) {
            const float4* w4 = (const float4*)(wr + kt * 32 + q * 8);
            float4 w0 = w4[0], w1 = w4[1];
            short8 v;
            v[0] = f2bf(w0.x * sc); v[1] = f2bf(w0.y * sc);
            v[2] = f2bf(w0.z * sc); v[3] = f2bf(w0.w * sc);
            v[4] = f2bf(w1.x * sc); v[5] = f2bf(w1.y * sc);
            v[6] = f2bf(w1.z * sc); v[7] = f2bf(w1.w * sc);
            bfrag[h][kt] = v;
        }
    }

    const int row = mtile * 16 + n16;
    const float* X = lig ? (lig_s + (size_t)row * kH)
                         : (pro_s + (size_t)(row - kRowsL) * kH);

    f32x4 acc[2] = {};
#pragma unroll
    for (int kt = 0; kt < 4; ++kt) {
        const float4* xp = (const float4*)(X + kt * 32 + q * 8);
        float4 x0 = xp[0], x1 = xp[1];
        short8 a;
        a[0] = f2bf(x0.x); a[1] = f2bf(x0.y); a[2] = f2bf(x0.z); a[3] = f2bf(x0.w);
        a[4] = f2bf(x1.x); a[5] = f2bf(x1.y); a[6] = f2bf(x1.z); a[7] = f2bf(x1.w);
        acc[0] = __builtin_amdgcn_mfma_f32_16x16x32_bf16(a, bfrag[0][kt], acc[0], 0, 0, 0);
        acc[1] = __builtin_amdgcn_mfma_f32_16x16x32_bf16(a, bfrag[1][kt], acc[1], 0, 0, 0);
    }

#pragma unroll
    for (int h = 0; h < 2; ++h) {
        const int c = (2 * wave + h) * 16 + n16;
#pragma unroll
        for (int r = 0; r < 4; ++r) {
            const int R = mtile * 16 + q * 4 + r;
            const float v = acc[h][r] + bi[h];
            if (lig) Al[(size_t)R * kH + c] = v;
            else     At[(size_t)(R - kRowsL) * kH + c] = v;
        }
    }
}

// ---------------------------------------------------------------------------
// pair: per wave, 32 consecutive pairs (2 mtiles) sharing one ligand row.
//   A-frag = bf16(elu(Al[bl]+At[pr])), weights resident as B-frags (48 VGPR)
//   loaded coalesced from the pre-packed Wcp image (round-5 measured winner).
//   Epilogue: softmax over the 16-lane n-group, elu+c, predicated stores;
//   dist + batch id fused on lanes 0..31.
// Grid: 384*4 blocks x 256 thr; block = (bl, 128-t chunk); wave = 32 t's.
// ---------------------------------------------------------------------------
__global__ __launch_bounds__(256) void pair_mfma(
    const float* __restrict__ Al, const float* __restrict__ At,
    const short* __restrict__ Wcp,
    const float* __restrict__ bpi, const float* __restrict__ bsg,
    const float* __restrict__ bmu,
    const float* __restrict__ lig_pos, const float* __restrict__ pro_pos,
    float* __restrict__ out)
{
    const int blk = blockIdx.x;
    const int bl = blk >> 2, tch = blk & 3;
    const int wave = threadIdx.x >> 6, lane = threadIdx.x & 63;
    const int q = lane >> 4, n = lane & 15;
    const int b = bl / kNL;
    const int t0 = tch * 128 + wave * 32;

    short8 bf[3][4];
    const short8* wp = (const short8*)Wcp;
#pragma unroll
    for (int kt = 0; kt < 4; ++kt)
#pragma unroll
        for (int ntl = 0; ntl < 3; ++ntl)
            bf[ntl][kt] = wp[(kt * 3 + ntl) * 64 + lane];

    const int nc = (n < kG) ? n : (kG - 1);
    const float bias0 = (n < kG) ? bpi[nc] : 0.0f;
    const float bias1 = (n < kG) ? bsg[nc] : 0.0f;
    const float bias2 = (n < kG) ? bmu[nc] : 0.0f;

    const float* alp = Al + (size_t)bl * kH;
    f32x4 acc[2][3] = {};

#pragma unroll
    for (int mt = 0; mt < 2; ++mt) {
        const int t = t0 + mt * 16 + n;
        const float* atp = At + (size_t)(b * kNT + t) * kH;
#pragma unroll
        for (int kt = 0; kt < 4; ++kt) {
            const float4* ap4 = (const float4*)(alp + kt * 32 + q * 8);
            const float4* tp4 = (const float4*)(atp + kt * 32 + q * 8);
            float4 a0 = ap4[0], a1 = ap4[1];
            float4 t0v = tp4[0], t1v = tp4[1];
            short8 a;
            a[0] = f2bf(elu_f(a0.x + t0v.x)); a[1] = f2bf(elu_f(a0.y + t0v.y));
            a[2] = f2bf(elu_f(a0.z + t0v.z)); a[3] = f2bf(elu_f(a0.w + t0v.w));
            a[4] = f2bf(elu_f(a1.x + t1v.x)); a[5] = f2bf(elu_f(a1.y + t1v.y));
            a[6] = f2bf(elu_f(a1.z + t1v.z)); a[7] = f2bf(elu_f(a1.w + t1v.w));
            acc[mt][0] = __builtin_amdgcn_mfma_f32_16x16x32_bf16(a, bf[0][kt], acc[mt][0], 0, 0, 0);
            acc[mt][1] = __builtin_amdgcn_mfma_f32_16x16x32_bf16(a, bf[1][kt], acc[mt][1], 0, 0, 0);
            acc[mt][2] = __builtin_amdgcn_mfma_f32_16x16x32_bf16(a, bf[2][kt], acc[mt][2], 0, 0, 0);
        }
    }

    const int pairbase = bl * kNT + t0;
#pragma unroll
    for (int mt = 0; mt < 2; ++mt) {
#pragma unroll
        for (int r = 0; r < 4; ++r) {
            const int m = pairbase + mt * 16 + q * 4 + r;
            // pi: masked softmax across the 16-lane n-group
            const float lg = acc[mt][0][r] + bias0;
            float mx = (n < kG) ? lg : -3.0e38f;
#pragma unroll
            for (int d = 1; d < 16; d <<= 1) mx = fmaxf(mx, __shfl_xor(mx, d));
            const float e = (n < kG) ? __expf(lg - mx) : 0.0f;
            float sm = e;
#pragma unroll
            for (int d = 1; d < 16; d <<= 1) sm += __shfl_xor(sm, d);
            if (n < kG) {
                out[OFF_PI + (size_t)m * kG + n] = e / sm;
                out[OFF_SG + (size_t)m * kG + n] = elu_f(acc[mt][1][r] + bias1) + 1.1f;
                out[OFF_MU + (size_t)m * kG + n] = elu_f(acc[mt][2][r] + bias2) + 1.0f;
            }
        }
    }

    // dist + batch id (lanes 0..31 cover the wave's 32 t's)
    if (lane < 32) {
        const int t = t0 + lane;
        const int pr = b * kNT + t;
        const int m = bl * kNT + t;
        const float dx = lig_pos[(size_t)bl * 3 + 0] - pro_pos[(size_t)pr * 3 + 0];
        const float dy = lig_pos[(size_t)bl * 3 + 1] - pro_pos[(size_t)pr * 3 + 1];
        const float dz = lig_pos[(size_t)bl * 3 + 2] - pro_pos[(size_t)pr * 3 + 2];
        out[OFF_D + m] = sqrtf(dx * dx + dy * dy + dz * dz);
        out[OFF_CB + m] = (float)b;
    }
}

extern "C" void kernel_launch(void* const* d_in, const int* in_sizes, int n_in,
                              void* d_out, int out_size, void* d_ws, size_t ws_size,
                              hipStream_t stream) {
    (void)in_sizes; (void)n_in; (void)out_size; (void)ws_size;
    const float* lig_s    = (const float*)d_in[0];
    const float* lig_pos  = (const float*)d_in[1];
    const float* pro_s    = (const float*)d_in[3];
    const float* pro_pos  = (const float*)d_in[4];
    const float* W1       = (const float*)d_in[6];
    const float* b1       = (const float*)d_in[7];
    const float* bn_gamma = (const float*)d_in[8];
    const float* bn_beta  = (const float*)d_in[9];
    const float* bn_mean  = (const float*)d_in[10];
    const float* bn_var   = (const float*)d_in[11];
    const float* W_pi     = (const float*)d_in[12];
    const float* b_pi     = (const float*)d_in[13];
    const float* W_sigma  = (const float*)d_in[14];
    const float* b_sigma  = (const float*)d_in[15];
    const float* W_mu     = (const float*)d_in[16];
    const float* b_mu     = (const float*)d_in[17];

    float* out = (float*)d_out;
    float* Al  = (float*)d_ws;                               // 384*128 f32
    float* At  = Al + (size_t)kRowsL * kH;                   // 4096*128 f32
    short* Wcp = (short*)(At + (size_t)kRowsT * kH);         // 4*3*64*8 bf16

    prep_sp<<<kRows / 16 + 1, 256, 0, stream>>>(
        lig_s, pro_s, W1, b1, bn_gamma, bn_beta, bn_mean, bn_var,
        W_pi, W_sigma, W_mu, Al, At, Wcp);
    pair_mfma<<<kRowsL * 4, 256, 0, stream>>>(Al, At, Wcp, b_pi, b_sigma, b_mu,
                                              lig_pos, pro_pos, out);
}